// Round 1
// baseline (125.937 us; speedup 1.0000x reference)
//
#include <hip/hip_runtime.h>

// etp: out[n, coff(l3)+m3, u] = sum_p sum_{m1,m2} cg_p[m1,m2,m3] * Y[n, yoff(l1)+m1]
//                               * H[n, coff(l2)+m2, u] * W[n, p, u]
// N=16384 edges, 16 channels (l=0..3, dims 1,3,5,7), MUL=128.
// Strategy: per-edge block (128 threads = 128 u). Phase 1: build
// B_p[m3][m2] = sum_m1 cg*y cooperatively into LDS (rows padded to 8 floats).
// Phase 2: each thread (one u) does acc[c3] += w_p * sum_m2 B*h. All global
// accesses coalesced (stride-1 in u across lanes); B reads are uniform LDS
// broadcasts.

#define BS 128
#define YD 16
#define HD 2048
#define WD 2944
#define NROW 99  // sum of d3 over paths (padded-B rows, stride 8 floats)

// X(p, l1, l2, l3, cg_offset, row_offset)
#define FOR_PATHS(X) \
  X(0, 0,0,0,    0,  0) \
  X(1, 0,1,1,    1,  1) \
  X(2, 0,2,2,   10,  4) \
  X(3, 0,3,3,   35,  9) \
  X(4, 1,0,1,   84, 16) \
  X(5, 1,1,0,   93, 19) \
  X(6, 1,1,2,  102, 20) \
  X(7, 1,2,1,  147, 25) \
  X(8, 1,2,3,  192, 28) \
  X(9, 1,3,2,  297, 35) \
  X(10,2,0,2,  402, 40) \
  X(11,2,1,1,  427, 45) \
  X(12,2,1,3,  472, 48) \
  X(13,2,2,0,  577, 55) \
  X(14,2,2,2,  602, 56) \
  X(15,2,3,1,  727, 61) \
  X(16,2,3,3,  832, 64) \
  X(17,3,0,3, 1077, 71) \
  X(18,3,1,2, 1126, 78) \
  X(19,3,2,1, 1231, 83) \
  X(20,3,2,3, 1336, 86) \
  X(21,3,3,0, 1581, 93) \
  X(22,3,3,2, 1630, 94)

__host__ __device__ constexpr int coff(int l) {
  return l == 0 ? 0 : (l == 1 ? 1 : (l == 2 ? 4 : 9));
}

__global__ __launch_bounds__(BS) void etp_kernel(
    const float* __restrict__ Y, const float* __restrict__ H,
    const float* __restrict__ W, const float* __restrict__ CG,
    float* __restrict__ O) {
  const int n = blockIdx.x;
  const int u = threadIdx.x;

  __shared__ __align__(16) float Bsm[NROW * 8];
  __shared__ float ysm[YD];

  if (u < YD) ysm[u] = Y[(size_t)n * YD + u];
  __syncthreads();

  // Phase 1: B_p[m3][m2] = sum_a cg_p[a,m2,m3] * y[coff(l1)+a]
  // One thread per (m3,m2) entry of each path (d2*d3 <= 49 < BS).
#define BUILD(P, L1, L2, L3, CGO, RO) { \
    constexpr int d1 = 2*(L1)+1, d2 = 2*(L2)+1, d3 = 2*(L3)+1; \
    if (u < d2 * d3) { \
      const int m3 = u / d2, m2 = u - m3 * d2; \
      float s = 0.f; \
      _Pragma("unroll") \
      for (int a = 0; a < d1; ++a) \
        s += CG[(CGO) + (a * d2 + m2) * d3 + m3] * ysm[coff(L1) + a]; \
      Bsm[((RO) + m3) * 8 + m2] = s; \
    } }
  FOR_PATHS(BUILD)
#undef BUILD
  __syncthreads();

  // Phase 2: per-u contraction.
  const size_t hbase = (size_t)n * HD + u;
  float h[YD];
#pragma unroll
  for (int c = 0; c < YD; ++c) h[c] = H[hbase + c * BS];

  float acc[YD];
#pragma unroll
  for (int c = 0; c < YD; ++c) acc[c] = 0.f;

  const size_t wbase = (size_t)n * WD + u;
#define DOPATH(P, L1, L2, L3, CGO, RO) { \
    constexpr int d2 = 2*(L2)+1, d3 = 2*(L3)+1; \
    const float wv = W[wbase + (P) * BS]; \
    _Pragma("unroll") \
    for (int m3 = 0; m3 < d3; ++m3) { \
      float s = 0.f; \
      _Pragma("unroll") \
      for (int m2 = 0; m2 < d2; ++m2) \
        s += Bsm[((RO) + m3) * 8 + m2] * h[coff(L2) + m2]; \
      acc[coff(L3) + m3] += s * wv; \
    } }
  FOR_PATHS(DOPATH)
#undef DOPATH

#pragma unroll
  for (int c = 0; c < YD; ++c) O[hbase + c * BS] = acc[c];
}

extern "C" void kernel_launch(void* const* d_in, const int* in_sizes, int n_in,
                              void* d_out, int out_size, void* d_ws, size_t ws_size,
                              hipStream_t stream) {
  const float* Y  = (const float*)d_in[0];
  const float* H  = (const float*)d_in[1];
  const float* W  = (const float*)d_in[2];
  const float* CG = (const float*)d_in[3];
  float* O = (float*)d_out;

  const int n_edges = in_sizes[0] / YD;
  etp_kernel<<<n_edges, BS, 0, stream>>>(Y, H, W, CG, O);
}

// Round 2
// 110.252 us; speedup vs baseline: 1.1423x; 1.1423x over previous
//
#include <hip/hip_runtime.h>

// etp: out[n, coff(l3)+m3, u] = sum_p sum_{m1,m2} cg_p[m1,m2,m3] * Y[n, yoff(l1)+m1]
//                               * H[n, coff(l2)+m2, u] * W[n, p, u]
// N=16384 edges, 16 channels (l=0..3, dims 1,3,5,7), MUL=128.
//
// R1: u vectorized by 4 (float4). 32 threads per edge (32 lanes x 4 u = 128),
// 4 edges per 128-thread block. Each LDS B-row read now feeds 4*d2 FMAs
// (was d2) -> LDS-pipe pressure /4, and all global accesses are 16 B/lane.

#define BS 128
#define GSZ 32   // threads per edge
#define EPB 4    // edges per block
#define YD 16
#define HD 2048
#define WD 2944
#define NROW 99  // sum of d3 over paths (B rows, padded to 8 floats each)

// X(p, l1, l2, l3, cg_offset, row_offset)
#define FOR_PATHS(X) \
  X(0, 0,0,0,    0,  0) \
  X(1, 0,1,1,    1,  1) \
  X(2, 0,2,2,   10,  4) \
  X(3, 0,3,3,   35,  9) \
  X(4, 1,0,1,   84, 16) \
  X(5, 1,1,0,   93, 19) \
  X(6, 1,1,2,  102, 20) \
  X(7, 1,2,1,  147, 25) \
  X(8, 1,2,3,  192, 28) \
  X(9, 1,3,2,  297, 35) \
  X(10,2,0,2,  402, 40) \
  X(11,2,1,1,  427, 45) \
  X(12,2,1,3,  472, 48) \
  X(13,2,2,0,  577, 55) \
  X(14,2,2,2,  602, 56) \
  X(15,2,3,1,  727, 61) \
  X(16,2,3,3,  832, 64) \
  X(17,3,0,3, 1077, 71) \
  X(18,3,1,2, 1126, 78) \
  X(19,3,2,1, 1231, 83) \
  X(20,3,2,3, 1336, 86) \
  X(21,3,3,0, 1581, 93) \
  X(22,3,3,2, 1630, 94)

__host__ __device__ constexpr int coff(int l) {
  return l == 0 ? 0 : (l == 1 ? 1 : (l == 2 ? 4 : 9));
}

__global__ __launch_bounds__(BS) void etp_kernel(
    const float* __restrict__ Y, const float* __restrict__ H,
    const float* __restrict__ W, const float* __restrict__ CG,
    float* __restrict__ O) {
  const int g = threadIdx.x >> 5;   // edge within block
  const int l = threadIdx.x & 31;   // lane within edge-group; owns u = 4l..4l+3
  const int n = blockIdx.x * EPB + g;

  __shared__ __align__(16) float Bsm[EPB][NROW * 8];
  __shared__ float ysm[EPB][YD];

  { const int t = threadIdx.x;
    if (t < EPB * YD) {
      const int e = t >> 4, c = t & 15;
      ysm[e][c] = Y[(size_t)(blockIdx.x * EPB + e) * YD + c];
    } }
  __syncthreads();

  // Phase 1: B_p[m3][m2] = sum_a cg_p[a,m2,m3] * y[coff(l1)+a], per edge-group.
#define BUILD(P, L1, L2, L3, CGO, RO) { \
    constexpr int d1 = 2*(L1)+1, d2 = 2*(L2)+1, d3 = 2*(L3)+1; \
    _Pragma("unroll") \
    for (int it = 0; it < (d2 * d3 + GSZ - 1) / GSZ; ++it) { \
      const int idx = l + it * GSZ; \
      if (idx < d2 * d3) { \
        const int m3 = idx / d2, m2 = idx - m3 * d2; \
        float s = 0.f; \
        _Pragma("unroll") \
        for (int a = 0; a < d1; ++a) \
          s += CG[(CGO) + (a * d2 + m2) * d3 + m3] * ysm[g][coff(L1) + a]; \
        Bsm[g][((RO) + m3) * 8 + m2] = s; \
      } } }
  FOR_PATHS(BUILD)
#undef BUILD
  __syncthreads();

  // Phase 2: per-lane contraction over 4 u's.
  const float4* __restrict__ Hp = (const float4*)(H + (size_t)n * HD);
  const float4* __restrict__ Wp = (const float4*)(W + (size_t)n * WD);
  float4* __restrict__ Op = (float4*)(O + (size_t)n * HD);

  float4 h[YD];
#pragma unroll
  for (int c = 0; c < YD; ++c) h[c] = Hp[c * GSZ + l];

  float4 acc[YD];
#pragma unroll
  for (int c = 0; c < YD; ++c) acc[c] = make_float4(0.f, 0.f, 0.f, 0.f);

#define DOPATH(P, L1, L2, L3, CGO, RO) { \
    constexpr int d2 = 2*(L2)+1, d3 = 2*(L3)+1; \
    const float4 wv = Wp[(P) * GSZ + l]; \
    _Pragma("unroll") \
    for (int m3 = 0; m3 < d3; ++m3) { \
      const float4* row = (const float4*)&Bsm[g][((RO) + m3) * 8]; \
      float br[8]; \
      *(float4*)&br[0] = row[0]; \
      if (d2 > 4) *(float4*)&br[4] = row[1]; \
      float4 s = make_float4(0.f, 0.f, 0.f, 0.f); \
      _Pragma("unroll") \
      for (int m2 = 0; m2 < d2; ++m2) { \
        const float b = br[m2]; \
        const float4 hv = h[coff(L2) + m2]; \
        s.x += b * hv.x; s.y += b * hv.y; s.z += b * hv.z; s.w += b * hv.w; \
      } \
      float4& A = acc[coff(L3) + m3]; \
      A.x += s.x * wv.x; A.y += s.y * wv.y; A.z += s.z * wv.z; A.w += s.w * wv.w; \
    } }
  FOR_PATHS(DOPATH)
#undef DOPATH

#pragma unroll
  for (int c = 0; c < YD; ++c) Op[c * GSZ + l] = acc[c];
}

extern "C" void kernel_launch(void* const* d_in, const int* in_sizes, int n_in,
                              void* d_out, int out_size, void* d_ws, size_t ws_size,
                              hipStream_t stream) {
  const float* Y  = (const float*)d_in[0];
  const float* H  = (const float*)d_in[1];
  const float* W  = (const float*)d_in[2];
  const float* CG = (const float*)d_in[3];
  float* O = (float*)d_out;

  const int n_edges = in_sizes[0] / YD;
  etp_kernel<<<n_edges / EPB, BS, 0, stream>>>(Y, H, W, CG, O);
}